// Round 5
// baseline (219.290 us; speedup 1.0000x reference)
//
#include <hip/hip_runtime.h>
#include <hip/hip_bf16.h>
#include <cstdint>
#include <cstddef>

#define B_ 2
#define N_ 2048
#define D_ 1024
#define H_ 16
#define DH_ 64
#define XYROWS 4095   /* N + (N-1) */
#define NL 12         /* self + 11 tree neighbors */
#define QKVN 3072     /* packed Q|K|V projection width */

typedef __attribute__((ext_vector_type(8))) short bf16x8;
typedef __attribute__((ext_vector_type(4))) float f32x4;

__device__ __forceinline__ float asf(unsigned int u) {
    union { unsigned int i; float f; } v; v.i = u; return v.f;
}
__device__ __forceinline__ unsigned short f2bf(float f) {
    union { float f; unsigned int i; } v; v.f = f;
    unsigned int u = v.i;
    unsigned int r = u + 0x7FFFu + ((u >> 16) & 1u);   // RNE
    return (unsigned short)(r >> 16);
}

// load 8 bf16 (16B) -> 8 fp32
__device__ __forceinline__ void ld8(const unsigned short* p, float* o) {
    uint4 u = *(const uint4*)p;
    o[0] = asf(u.x << 16); o[1] = asf(u.x & 0xffff0000u);
    o[2] = asf(u.y << 16); o[3] = asf(u.y & 0xffff0000u);
    o[4] = asf(u.z << 16); o[5] = asf(u.z & 0xffff0000u);
    o[6] = asf(u.w << 16); o[7] = asf(u.w & 0xffff0000u);
}

// async global->LDS 16B per lane; lds base wave-uniform, HW scatters lane l
// to base + l*16.
__device__ __forceinline__ void gload_lds16(const unsigned short* g, unsigned short* l) {
    __builtin_amdgcn_global_load_lds(
        (const __attribute__((address_space(1))) unsigned int*)g,
        (__attribute__((address_space(3))) unsigned int*)l,
        16, 0, 0);
}

// ---- fused prep: build xy (bf16) + convert all four weight matrices ----
__global__ void prep_kernel(const float* __restrict__ q, const float* __restrict__ y,
                            const float* __restrict__ Wq, const float* __restrict__ Wk,
                            const float* __restrict__ Wv, const float* __restrict__ Wo,
                            unsigned short* __restrict__ xy,
                            unsigned short* __restrict__ wqkv, unsigned short* __restrict__ wob) {
    int c = blockIdx.x * blockDim.x + threadIdx.x;   // chunk of 8 elems
    constexpr int TOTAL_XY = B_ * XYROWS * (D_ / 8); // 1048320
    constexpr int TOTAL_W  = 4 * 131072;             // 524288
    if (c >= TOTAL_XY + TOTAL_W) return;
    const float* src;
    unsigned short* dst;
    if (c < TOTAL_XY) {
        int col8 = (c & (D_ / 8 - 1)) * 8;
        int rg = c >> 7;                              // global row 0..B*4095-1
        int b = (rg >= XYROWS) ? 1 : 0;
        int r = rg - b * XYROWS;
        if (r < N_) src = q + ((size_t)b * N_ + r) * D_ + col8;
        else        src = y + ((size_t)b * (N_ - 1) + (r - N_)) * D_ + col8;
        dst = xy + (size_t)rg * D_ + col8;
    } else {
        int idx = c - TOTAL_XY;
        int which = idx >> 17;
        int sub = idx & 131071;
        const float* w = (which == 0) ? Wq : (which == 1) ? Wk : (which == 2) ? Wv : Wo;
        src = w + (size_t)sub * 8;
        dst = ((which < 3) ? (wqkv + (size_t)which * D_ * D_) : wob) + (size_t)sub * 8;
    }
    float4 a = *(const float4*)(src);
    float4 bb = *(const float4*)(src + 4);
    union { unsigned short us[8]; uint4 u4; } o;
    o.us[0] = f2bf(a.x);  o.us[1] = f2bf(a.y);  o.us[2] = f2bf(a.z);  o.us[3] = f2bf(a.w);
    o.us[4] = f2bf(bb.x); o.us[5] = f2bf(bb.y); o.us[6] = f2bf(bb.z); o.us[7] = f2bf(bb.w);
    *(uint4*)(dst) = o.u4;
}

// --------------------------- bf16 GEMM: C = A @ W^T -----------------------
// A: M x 1024 bf16 row-major; W: Nn x 1024 bf16 row-major.
// BM x 128 block tile, 4 waves (2x2), (BM/2)x64 per wave via MFMA 16x16x32.
// BM=192 raises compute intensity (78 FLOP/B from L2) so the L2-fetch and
// LDS-read pipes sit below the MFMA pipe; 40 KB LDS + <=170 VGPR keeps 3
// blocks/CU resident to de-phase the barrier rhythm.
// Staging: global_load_lds width=16, XOR-swizzled chunk order (0 bank conflicts).
// QSKIP: skip Q columns (col0<1024) on row tiles holding only y-positions.
template<int BM, bool OUTF32, bool BIAS, bool QSKIP>
__global__ __launch_bounds__(256, 3)
void gemm_bt(const unsigned short* __restrict__ A, const unsigned short* __restrict__ W,
             void* __restrict__ Cv, const float* __restrict__ bias, int M, int Nn) {
    constexpr int K = 1024, BK = 64;
    constexpr int IM = BM / 32;          // mfma row-tiles per wave
    __shared__ __align__(16) unsigned short la[BM * 64];
    __shared__ __align__(16) unsigned short lb[128 * 64];

    int row0 = blockIdx.x * BM;
    int col0 = blockIdx.y * 128;
    if (QSKIP && col0 < 1024) {
        int t = blockIdx.x;                 // y-only row tiles for BM=192:
        if ((t >= 11 && t <= 20) || t >= 32) return;
    }
    int tid = threadIdx.x;
    int wave = tid >> 6, lane = tid & 63;
    int wm = wave >> 1, wn = wave & 1;
    int q4 = lane >> 4, r = lane & 15;

    // staging: lane l supplies row l/8 of its segment; fetched chunk is
    // XOR-swizzled by the row's low 3 bits.
    int rsub = lane >> 3;                         // 0..7
    int csw = ((lane & 7) ^ rsub) * 8;            // swizzled source chunk col

    f32x4 acc[IM][4];
    f32x4 zero = {0.f, 0.f, 0.f, 0.f};
#pragma unroll
    for (int i = 0; i < IM; i++)
#pragma unroll
        for (int j = 0; j < 4; j++) acc[i][j] = zero;

    for (int k0 = 0; k0 < K; k0 += BK) {
#pragma unroll
        for (int p = 0; p < IM / 2; p++) {        // A: BM/8 segs, IM/2 per wave... (IM/2*4 waves = BM/8? no)
        }
#pragma unroll
        for (int p = 0; p < IM; p++) {            // A: BM/8 = 4*IM/... segs: wave*IM/?  — IM segs per wave covers 4*IM*8 = BM rows? 4*IM*8 = BM*... (IM=BM/32 -> 4*IM = BM/8 segs total)
            int seg = wave * IM + p;              // 0..BM/8-1 when p<IM/... p<IM gives 4*IM = BM/8 segs? 4*IM = BM/8  ✓ (BM/8 = 4*BM/32)
            int ar = row0 + seg * 8 + rsub; if (ar >= M) ar = M - 1;
            gload_lds16(A + (size_t)ar * K + k0 + csw, &la[seg * 512]);
        }
#pragma unroll
        for (int p = 0; p < 4; p++) {             // B: 16 segs, 4 per wave
            int seg = wave * 4 + p;
            gload_lds16(W + (size_t)(col0 + seg * 8 + rsub) * K + k0 + csw, &lb[seg * 512]);
        }
        __syncthreads();
#pragma unroll
        for (int ks = 0; ks < 2; ks++) {
            int cidx = ks * 4 + q4;
            bf16x8 af[IM], bfv[4];
#pragma unroll
            for (int j = 0; j < 4; j++) {
                int rb = wn * 64 + j * 16 + r;
                bfv[j] = *(const bf16x8*)(&lb[rb * 64 + ((cidx ^ (rb & 7)) << 3)]);
            }
#pragma unroll
            for (int i = 0; i < IM; i++) {
                int rr = wm * (BM / 2) + i * 16 + r;
                af[i] = *(const bf16x8*)(&la[rr * 64 + ((cidx ^ (rr & 7)) << 3)]);
            }
#pragma unroll
            for (int i = 0; i < IM; i++)
#pragma unroll
                for (int j = 0; j < 4; j++)
                    acc[i][j] = __builtin_amdgcn_mfma_f32_16x16x32_bf16(af[i], bfv[j], acc[i][j], 0, 0, 0);
        }
        __syncthreads();
    }

    float bv[4];
    if (BIAS) {
#pragma unroll
        for (int j = 0; j < 4; j++) bv[j] = bias[col0 + wn * 64 + j * 16 + r];
    }
#pragma unroll
    for (int i = 0; i < IM; i++) {
#pragma unroll
        for (int j = 0; j < 4; j++) {
            int col = col0 + wn * 64 + j * 16 + r;
#pragma unroll
            for (int reg = 0; reg < 4; reg++) {
                int row = row0 + wm * (BM / 2) + i * 16 + q4 * 4 + reg;
                if (row < M) {
                    float v = acc[i][j][reg];
                    if (BIAS) v += bv[j];
                    if (OUTF32)
                        ((float*)Cv)[(size_t)row * Nn + col] = v;
                    else
                        ((unsigned short*)Cv)[(size_t)row * Nn + col] = f2bf(v);
                }
            }
        }
    }
}

// ----------------------- hierarchical sparse attention --------------------
// One block per (query-pair, batch); queries 2i,2i+1 share all 12 rows.
// QKV layout: per xy-row, 3072 cols = [Q | K | V].
__global__ __launch_bounds__(256)
void attn_kernel(const unsigned short* __restrict__ QKV, unsigned short* __restrict__ O) {
    int t = threadIdx.x;
    int half = t >> 7;           // which query of the pair
    int c = t & 127;             // 8-dim chunk 0..127
    int b = blockIdx.y;
    int n = blockIdx.x * 2 + half;

    int rows[NL];
    rows[0] = n;
    int cur = n ^ 1;
    rows[1] = cur;
#pragma unroll
    for (int l = 1; l < 11; l++) {
        cur = ((cur >> 1) + N_) ^ 1;
        rows[l + 1] = cur;
    }

    const unsigned short* base = QKV + (size_t)b * XYROWS * QKVN;
    size_t c8 = (size_t)c * 8;

    float q[8];
    ld8(base + (size_t)n * QKVN + c8, q);

    float logits[NL];
#pragma unroll
    for (int j = 0; j < NL; j++) {
        float kv[8];
        ld8(base + (size_t)rows[j] * QKVN + D_ + c8, kv);
        float p = 0.f;
#pragma unroll
        for (int e = 0; e < 8; e++) p = fmaf(q[e], kv[e], p);
        p += __shfl_xor(p, 1);
        p += __shfl_xor(p, 2);
        p += __shfl_xor(p, 4);
        logits[j] = p * 0.125f;   // 1/sqrt(64)
    }

    float mx = logits[0];
#pragma unroll
    for (int j = 1; j < NL; j++) mx = fmaxf(mx, logits[j]);
    float s = 0.f, w[NL];
#pragma unroll
    for (int j = 0; j < NL; j++) { w[j] = __expf(logits[j] - mx); s += w[j]; }
    float inv = 1.f / s;

    float acc[8] = {0.f, 0.f, 0.f, 0.f, 0.f, 0.f, 0.f, 0.f};
#pragma unroll
    for (int j = 0; j < NL; j++) {
        float vv[8];
        ld8(base + (size_t)rows[j] * QKVN + 2 * D_ + c8, vv);
        float wj = w[j] * inv;
#pragma unroll
        for (int e = 0; e < 8; e++) acc[e] = fmaf(wj, vv[e], acc[e]);
    }

    union { unsigned short us[8]; uint4 u4; } o;
#pragma unroll
    for (int e = 0; e < 8; e++) o.us[e] = f2bf(acc[e]);
    *(uint4*)(O + ((size_t)b * N_ + n) * D_ + c8) = o.u4;
}

extern "C" void kernel_launch(void* const* d_in, const int* in_sizes, int n_in,
                              void* d_out, int out_size, void* d_ws, size_t ws_size,
                              hipStream_t stream) {
    const float* query = (const float*)d_in[0];
    // d_in[1] (key), d_in[2] (value) are unused by the reference
    const float* y  = (const float*)d_in[3];
    const float* Wq = (const float*)d_in[4];
    const float* Wk = (const float*)d_in[5];
    const float* Wv = (const float*)d_in[6];
    const float* Wo = (const float*)d_in[7];
    const float* bo = (const float*)d_in[8];
    float* out = (float*)d_out;

    char* ws = (char*)d_ws;
    size_t off = 0;
    auto alloc = [&](size_t bytes) {
        void* p = ws + off; off += (bytes + 255) & ~(size_t)255; return p;
    };
    unsigned short* xy   = (unsigned short*)alloc((size_t)B_ * XYROWS * D_ * 2 + 147456); // pad: OOB tile rows (BM=192 overshoot)
    unsigned short* wqkv = (unsigned short*)alloc((size_t)QKVN * D_ * 2);
    unsigned short* wob  = (unsigned short*)alloc((size_t)D_ * D_ * 2);
    unsigned short* QKV  = (unsigned short*)alloc((size_t)B_ * XYROWS * QKVN * 2);
    unsigned short* At   = (unsigned short*)alloc((size_t)B_ * N_ * D_ * 2);

    // 1. fused prep: xy (bf16) + all weight conversions
    prep_kernel<<<6144, 256, 0, stream>>>(query, y, Wq, Wk, Wv, Wo, xy, wqkv, wob);

    // 2. fused QKV projection, BM=192 (skips Q cols on y-only row tiles)
    {
        dim3 g((B_ * XYROWS + 191) / 192, QKVN / 128);
        gemm_bt<192, false, false, true><<<g, 256, 0, stream>>>(
            xy, wqkv, QKV, nullptr, B_ * XYROWS, QKVN);
    }
    // 3. hierarchical attention (paired queries)
    {
        dim3 g(N_ / 2, B_);
        attn_kernel<<<g, 256, 0, stream>>>(QKV, At);
    }
    // 4. output projection + bias (fp32 out), 64-row tiles -> 512 blocks
    {
        dim3 g((B_ * N_) / 64, D_ / 128);
        gemm_bt<64, true, true, false><<<g, 256, 0, stream>>>(At, wob, out, bo, B_ * N_, D_);
    }
}

// Round 6
// 211.654 us; speedup vs baseline: 1.0361x; 1.0361x over previous
//
#include <hip/hip_runtime.h>
#include <hip/hip_bf16.h>
#include <cstdint>
#include <cstddef>

#define B_ 2
#define N_ 2048
#define D_ 1024
#define H_ 16
#define DH_ 64
#define XYROWS 4095   /* N + (N-1) */
#define NL 12         /* self + 11 tree neighbors */
#define QKVN 3072     /* packed Q|K|V projection width */

typedef __attribute__((ext_vector_type(8))) short bf16x8;
typedef __attribute__((ext_vector_type(4))) float f32x4;

__device__ __forceinline__ float asf(unsigned int u) {
    union { unsigned int i; float f; } v; v.i = u; return v.f;
}
__device__ __forceinline__ unsigned short f2bf(float f) {
    union { float f; unsigned int i; } v; v.f = f;
    unsigned int u = v.i;
    unsigned int r = u + 0x7FFFu + ((u >> 16) & 1u);   // RNE
    return (unsigned short)(r >> 16);
}

// load 8 bf16 (16B) -> 8 fp32
__device__ __forceinline__ void ld8(const unsigned short* p, float* o) {
    uint4 u = *(const uint4*)p;
    o[0] = asf(u.x << 16); o[1] = asf(u.x & 0xffff0000u);
    o[2] = asf(u.y << 16); o[3] = asf(u.y & 0xffff0000u);
    o[4] = asf(u.z << 16); o[5] = asf(u.z & 0xffff0000u);
    o[6] = asf(u.w << 16); o[7] = asf(u.w & 0xffff0000u);
}

// async global->LDS 16B per lane; lds base wave-uniform, HW scatters lane l
// to base + l*16.
__device__ __forceinline__ void gload_lds16(const unsigned short* g, unsigned short* l) {
    __builtin_amdgcn_global_load_lds(
        (const __attribute__((address_space(1))) unsigned int*)g,
        (__attribute__((address_space(3))) unsigned int*)l,
        16, 0, 0);
}

// ---- fused prep: build xy (bf16) + convert all four weight matrices ----
__global__ void prep_kernel(const float* __restrict__ q, const float* __restrict__ y,
                            const float* __restrict__ Wq, const float* __restrict__ Wk,
                            const float* __restrict__ Wv, const float* __restrict__ Wo,
                            unsigned short* __restrict__ xy,
                            unsigned short* __restrict__ wqkv, unsigned short* __restrict__ wob) {
    int c = blockIdx.x * blockDim.x + threadIdx.x;   // chunk of 8 elems
    constexpr int TOTAL_XY = B_ * XYROWS * (D_ / 8); // 1048320
    constexpr int TOTAL_W  = 4 * 131072;             // 524288
    if (c >= TOTAL_XY + TOTAL_W) return;
    const float* src;
    unsigned short* dst;
    if (c < TOTAL_XY) {
        int col8 = (c & (D_ / 8 - 1)) * 8;
        int rg = c >> 7;                              // global row 0..B*4095-1
        int b = (rg >= XYROWS) ? 1 : 0;
        int r = rg - b * XYROWS;
        if (r < N_) src = q + ((size_t)b * N_ + r) * D_ + col8;
        else        src = y + ((size_t)b * (N_ - 1) + (r - N_)) * D_ + col8;
        dst = xy + (size_t)rg * D_ + col8;
    } else {
        int idx = c - TOTAL_XY;
        int which = idx >> 17;
        int sub = idx & 131071;
        const float* w = (which == 0) ? Wq : (which == 1) ? Wk : (which == 2) ? Wv : Wo;
        src = w + (size_t)sub * 8;
        dst = ((which < 3) ? (wqkv + (size_t)which * D_ * D_) : wob) + (size_t)sub * 8;
    }
    float4 a = *(const float4*)(src);
    float4 bb = *(const float4*)(src + 4);
    union { unsigned short us[8]; uint4 u4; } o;
    o.us[0] = f2bf(a.x);  o.us[1] = f2bf(a.y);  o.us[2] = f2bf(a.z);  o.us[3] = f2bf(a.w);
    o.us[4] = f2bf(bb.x); o.us[5] = f2bf(bb.y); o.us[6] = f2bf(bb.z); o.us[7] = f2bf(bb.w);
    *(uint4*)(dst) = o.u4;
}

// --------------------------- bf16 GEMM: C = A @ W^T -----------------------
// A: M x 1024 bf16 row-major; W: Nn x 1024 bf16 row-major.
// BM x 128 block tile, 4 waves (2x2), (BM/2)x64 per wave via MFMA 16x16x32.
// *** gridDim.x MUST be a multiple of 8 ***: XCD = linear-block-id % 8, so a
// multiple-of-8 grid.x pins each x-tile's A-slice to one XCD L2 across all
// col-tiles (round-5 lesson: grid.x=43 scattered x over XCDs -> 8x A-fetch,
// FETCH 41.5 -> 138.9 MB, 55 -> 74 us). Pad with row0>=M dummy tiles.
// Staging: global_load_lds width=16, XOR-swizzled chunk order (0 bank conflicts).
// QSKIP: skip Q columns (col0<1024) on row tiles holding only y-positions.
template<int BM, bool OUTF32, bool BIAS, bool QSKIP>
__global__ __launch_bounds__(256, 3)
void gemm_bt(const unsigned short* __restrict__ A, const unsigned short* __restrict__ W,
             void* __restrict__ Cv, const float* __restrict__ bias, int M, int Nn) {
    constexpr int K = 1024, BK = 64;
    constexpr int IM = BM / 32;          // mfma row-tiles per wave
    __shared__ __align__(16) unsigned short la[BM * 64];
    __shared__ __align__(16) unsigned short lb[128 * 64];

    int row0 = blockIdx.x * BM;
    if (row0 >= M) return;                  // grid.x padded to a multiple of 8
    int col0 = blockIdx.y * 128;
    if (QSKIP && col0 < 1024) {
        int t = blockIdx.x;                 // y-only row tiles for BM=192:
        if ((t >= 11 && t <= 20) || t >= 32) return;
    }
    int tid = threadIdx.x;
    int wave = tid >> 6, lane = tid & 63;
    int wm = wave >> 1, wn = wave & 1;
    int q4 = lane >> 4, r = lane & 15;

    // staging: lane l supplies row l/8 of its segment; fetched chunk is
    // XOR-swizzled by the row's low 3 bits.
    int rsub = lane >> 3;                         // 0..7
    int csw = ((lane & 7) ^ rsub) * 8;            // swizzled source chunk col

    f32x4 acc[IM][4];
    f32x4 zero = {0.f, 0.f, 0.f, 0.f};
#pragma unroll
    for (int i = 0; i < IM; i++)
#pragma unroll
        for (int j = 0; j < 4; j++) acc[i][j] = zero;

    for (int k0 = 0; k0 < K; k0 += BK) {
#pragma unroll
        for (int p = 0; p < IM; p++) {            // A: 4*IM = BM/8 segments
            int seg = wave * IM + p;
            int ar = row0 + seg * 8 + rsub; if (ar >= M) ar = M - 1;
            gload_lds16(A + (size_t)ar * K + k0 + csw, &la[seg * 512]);
        }
#pragma unroll
        for (int p = 0; p < 4; p++) {             // B: 16 segs, 4 per wave
            int seg = wave * 4 + p;
            gload_lds16(W + (size_t)(col0 + seg * 8 + rsub) * K + k0 + csw, &lb[seg * 512]);
        }
        __syncthreads();
#pragma unroll
        for (int ks = 0; ks < 2; ks++) {
            int cidx = ks * 4 + q4;
            bf16x8 af[IM], bfv[4];
#pragma unroll
            for (int j = 0; j < 4; j++) {
                int rb = wn * 64 + j * 16 + r;
                bfv[j] = *(const bf16x8*)(&lb[rb * 64 + ((cidx ^ (rb & 7)) << 3)]);
            }
#pragma unroll
            for (int i = 0; i < IM; i++) {
                int rr = wm * (BM / 2) + i * 16 + r;
                af[i] = *(const bf16x8*)(&la[rr * 64 + ((cidx ^ (rr & 7)) << 3)]);
            }
#pragma unroll
            for (int i = 0; i < IM; i++)
#pragma unroll
                for (int j = 0; j < 4; j++)
                    acc[i][j] = __builtin_amdgcn_mfma_f32_16x16x32_bf16(af[i], bfv[j], acc[i][j], 0, 0, 0);
        }
        __syncthreads();
    }

    float bv[4];
    if (BIAS) {
#pragma unroll
        for (int j = 0; j < 4; j++) bv[j] = bias[col0 + wn * 64 + j * 16 + r];
    }
#pragma unroll
    for (int i = 0; i < IM; i++) {
#pragma unroll
        for (int j = 0; j < 4; j++) {
            int col = col0 + wn * 64 + j * 16 + r;
#pragma unroll
            for (int reg = 0; reg < 4; reg++) {
                int row = row0 + wm * (BM / 2) + i * 16 + q4 * 4 + reg;
                if (row < M) {
                    float v = acc[i][j][reg];
                    if (BIAS) v += bv[j];
                    if (OUTF32)
                        ((float*)Cv)[(size_t)row * Nn + col] = v;
                    else
                        ((unsigned short*)Cv)[(size_t)row * Nn + col] = f2bf(v);
                }
            }
        }
    }
}

// ----------------------- hierarchical sparse attention --------------------
// One block per (query-pair, batch); queries 2i,2i+1 share all 12 rows.
// QKV layout: per xy-row, 3072 cols = [Q | K | V].
__global__ __launch_bounds__(256)
void attn_kernel(const unsigned short* __restrict__ QKV, unsigned short* __restrict__ O) {
    int t = threadIdx.x;
    int half = t >> 7;           // which query of the pair
    int c = t & 127;             // 8-dim chunk 0..127
    int b = blockIdx.y;
    int n = blockIdx.x * 2 + half;

    int rows[NL];
    rows[0] = n;
    int cur = n ^ 1;
    rows[1] = cur;
#pragma unroll
    for (int l = 1; l < 11; l++) {
        cur = ((cur >> 1) + N_) ^ 1;
        rows[l + 1] = cur;
    }

    const unsigned short* base = QKV + (size_t)b * XYROWS * QKVN;
    size_t c8 = (size_t)c * 8;

    float q[8];
    ld8(base + (size_t)n * QKVN + c8, q);

    float logits[NL];
#pragma unroll
    for (int j = 0; j < NL; j++) {
        float kv[8];
        ld8(base + (size_t)rows[j] * QKVN + D_ + c8, kv);
        float p = 0.f;
#pragma unroll
        for (int e = 0; e < 8; e++) p = fmaf(q[e], kv[e], p);
        p += __shfl_xor(p, 1);
        p += __shfl_xor(p, 2);
        p += __shfl_xor(p, 4);
        logits[j] = p * 0.125f;   // 1/sqrt(64)
    }

    float mx = logits[0];
#pragma unroll
    for (int j = 1; j < NL; j++) mx = fmaxf(mx, logits[j]);
    float s = 0.f, w[NL];
#pragma unroll
    for (int j = 0; j < NL; j++) { w[j] = __expf(logits[j] - mx); s += w[j]; }
    float inv = 1.f / s;

    float acc[8] = {0.f, 0.f, 0.f, 0.f, 0.f, 0.f, 0.f, 0.f};
#pragma unroll
    for (int j = 0; j < NL; j++) {
        float vv[8];
        ld8(base + (size_t)rows[j] * QKVN + 2 * D_ + c8, vv);
        float wj = w[j] * inv;
#pragma unroll
        for (int e = 0; e < 8; e++) acc[e] = fmaf(wj, vv[e], acc[e]);
    }

    union { unsigned short us[8]; uint4 u4; } o;
#pragma unroll
    for (int e = 0; e < 8; e++) o.us[e] = f2bf(acc[e]);
    *(uint4*)(O + ((size_t)b * N_ + n) * D_ + c8) = o.u4;
}

extern "C" void kernel_launch(void* const* d_in, const int* in_sizes, int n_in,
                              void* d_out, int out_size, void* d_ws, size_t ws_size,
                              hipStream_t stream) {
    const float* query = (const float*)d_in[0];
    // d_in[1] (key), d_in[2] (value) are unused by the reference
    const float* y  = (const float*)d_in[3];
    const float* Wq = (const float*)d_in[4];
    const float* Wk = (const float*)d_in[5];
    const float* Wv = (const float*)d_in[6];
    const float* Wo = (const float*)d_in[7];
    const float* bo = (const float*)d_in[8];
    float* out = (float*)d_out;

    char* ws = (char*)d_ws;
    size_t off = 0;
    auto alloc = [&](size_t bytes) {
        void* p = ws + off; off += (bytes + 255) & ~(size_t)255; return p;
    };
    unsigned short* xy   = (unsigned short*)alloc((size_t)B_ * XYROWS * D_ * 2 + 147456); // pad: OOB tile rows (BM=192 overshoot)
    unsigned short* wqkv = (unsigned short*)alloc((size_t)QKVN * D_ * 2);
    unsigned short* wob  = (unsigned short*)alloc((size_t)D_ * D_ * 2);
    unsigned short* QKV  = (unsigned short*)alloc((size_t)B_ * XYROWS * QKVN * 2);
    unsigned short* At   = (unsigned short*)alloc((size_t)B_ * N_ * D_ * 2);

    // 1. fused prep: xy (bf16) + all weight conversions
    prep_kernel<<<6144, 256, 0, stream>>>(query, y, Wq, Wk, Wv, Wo, xy, wqkv, wob);

    // 2. fused QKV projection, BM=192; grid.x padded 43 -> 48 (mult of 8) so
    //    XCD = x%8 and each XCD's A-slice stays L2-resident across col-tiles.
    {
        dim3 g(48, QKVN / 128);
        gemm_bt<192, false, false, true><<<g, 256, 0, stream>>>(
            xy, wqkv, QKV, nullptr, B_ * XYROWS, QKVN);
    }
    // 3. hierarchical attention (paired queries)
    {
        dim3 g(N_ / 2, B_);
        attn_kernel<<<g, 256, 0, stream>>>(QKV, At);
    }
    // 4. output projection + bias (fp32 out), BM=64 -> grid.x 64 (mult of 8)
    {
        dim3 g((B_ * N_) / 64, D_ / 128);
        gemm_bt<64, true, true, false><<<g, 256, 0, stream>>>(At, wob, out, bo, B_ * N_, D_);
    }
}